// Round 4
// baseline (1157.430 us; speedup 1.0000x reference)
//
#include <hip/hip_runtime.h>

#define NN 32768   // nodes
#define NB 256     // graphs
#define HD 128     // hidden
#define NL 4       // layers
#define NE 262144  // edges

typedef short bf16x8 __attribute__((ext_vector_type(8)));
typedef float f32x4 __attribute__((ext_vector_type(4)));
typedef unsigned short u16;
typedef unsigned int u32;

__device__ __forceinline__ float bf2f(u16 u) {
  return __uint_as_float(((u32)u) << 16);
}
__device__ __forceinline__ u16 f2bf(float f) {
  u32 x = __float_as_uint(f);
  u32 r = x + 0x7FFFu + ((x >> 16) & 1u);
  return (u16)(r >> 16);
}
__device__ __forceinline__ u32 pk2(float a, float b) {
  return (u32)f2bf(a) | ((u32)f2bf(b) << 16);
}
__device__ __forceinline__ float siluf(float x) {
  return x * __builtin_amdgcn_rcpf(1.0f + __expf(-x));
}
__device__ __forceinline__ float sigf(float x) {
  return __builtin_amdgcn_rcpf(1.0f + __expf(-x));
}
__device__ __forceinline__ u32 ordu(float f) {
  u32 b = __float_as_uint(f);
  return (b & 0x80000000u) ? ~b : (b | 0x80000000u);
}

// ---- adaptive input loads: mode 1 = f32 inputs, mode 0 = bf16 inputs ----
__device__ __forceinline__ float ldinf(const void* p, size_t i, int mode) {
  return mode ? ((const float*)p)[i] : bf2f(((const u16*)p)[i]);
}
__device__ __forceinline__ u16 ldinb(const void* p, size_t i, int mode) {
  return mode ? f2bf(((const float*)p)[i]) : ((const u16*)p)[i];
}

// ---- dtype detector (confirmed mode=1/f32; kept as cheap guard) ----
__global__ void k_detect(const u16* __restrict__ Weraw, int* __restrict__ flag) {
  if (threadIdx.x == 0 && blockIdx.x == 0) {
    int cnt = 0;
    for (int i = 0; i < 256; i++) {
      u16 u = Weraw[2 * i];
      u32 e = (u >> 7) & 0xFFu;
      if (e >= 112u && e <= 126u) cnt++;
    }
    *flag = (cnt >= 128) ? 0 : 1;
  }
}

// ---------------- per-wave GEMM pieces ----------------
// Wave tile: 64 rows x 128 cols, mfma_f32_16x16x32_bf16.
// A-frag: lane l holds A[row=(l&15)+16*mt][k=(l>>4)*8+j]  (16B contiguous)
// C/D: col = lane&15, row = (lane>>4)*4 + reg  (m89-verified)
// LDS tile (h1/m only): [64 rows][128 shorts], XOR-swizzled 16B granules:
//   granule_lds = granule_logical ^ (row & 7)
// Packed k_new order: granule g element j <-> h = j*16 + g

__device__ __forceinline__ void acc_zero(f32x4 (&acc)[4][8]) {
#pragma unroll
  for (int mt = 0; mt < 4; mt++)
#pragma unroll
    for (int nt = 0; nt < 8; nt++) acc[mt][nt] = f32x4{0.f, 0.f, 0.f, 0.f};
}

// GEMM with A-fragments loaded DIRECTLY from global rows (no LDS staging).
template <int BSTRIDE>
__device__ __forceinline__ void gemm_g(const u16* __restrict__ A0,
                                       const size_t* rowoff,
                                       const u16* __restrict__ Bp,
                                       int c, int kg, f32x4 (&acc)[4][8]) {
#pragma unroll
  for (int ks = 0; ks < 4; ks++) {
    bf16x8 a[4];
#pragma unroll
    for (int mt = 0; mt < 4; mt++)
      a[mt] = *(const bf16x8*)&A0[rowoff[mt] + ks * 32 + kg * 8];
#pragma unroll
    for (int nt = 0; nt < 8; nt++) {
      bf16x8 b = *(const bf16x8*)&Bp[(nt * 16 + c) * BSTRIDE + ks * 32 + kg * 8];
#pragma unroll
      for (int mt = 0; mt < 4; mt++)
        acc[mt][nt] = __builtin_amdgcn_mfma_f32_16x16x32_bf16(a[mt], b, acc[mt][nt], 0, 0, 0);
    }
  }
}

// GEMM with A from swizzled LDS tile (for h1 @ W2 etc.)
template <int KSTEPS, int BSTRIDE>
__device__ __forceinline__ void wave_gemm(const short* lAw, const u16* Bp,
                                          int c, int kg, f32x4 (&acc)[4][8]) {
#pragma unroll
  for (int ks = 0; ks < KSTEPS; ks++) {
    bf16x8 a[4];
#pragma unroll
    for (int mt = 0; mt < 4; mt++) {
      const int r = mt * 16 + c;
      const int k = ks * 32 + kg * 8;
      a[mt] = *(const bf16x8*)&lAw[r * HD + (k ^ ((r & 7) << 3))];
    }
#pragma unroll
    for (int nt = 0; nt < 8; nt++) {
      bf16x8 b = *(const bf16x8*)&Bp[(nt * 16 + c) * BSTRIDE + ks * 32 + kg * 8];
#pragma unroll
      for (int mt = 0; mt < 4; mt++)
        acc[mt][nt] = __builtin_amdgcn_mfma_f32_16x16x32_bf16(a[mt], b, acc[mt][nt], 0, 0, 0);
    }
  }
}

template <bool SILU>
__device__ __forceinline__ void wave_pack(short* lAw, int c, int kg,
                                          f32x4 (&acc)[4][8], const float* bias) {
#pragma unroll
  for (int mt = 0; mt < 4; mt++) {
#pragma unroll
    for (int rr = 0; rr < 4; rr++) {
      const int row = mt * 16 + kg * 4 + rr;
      u32 ou[4];
#pragma unroll
      for (int p = 0; p < 4; p++) {
        float x0 = acc[mt][2 * p][rr] + bias[2 * p];
        float x1 = acc[mt][2 * p + 1][rr] + bias[2 * p + 1];
        if (SILU) { x0 = siluf(x0); x1 = siluf(x1); }
        ou[p] = pk2(x0, x1);
      }
      ((int4*)(lAw + row * HD))[c ^ (row & 7)] =
          make_int4((int)ou[0], (int)ou[1], (int)ou[2], (int)ou[3]);
    }
  }
}

// Read back one packed LDS row (k_new order) into h-order floats.
__device__ __forceinline__ void read_row_h(const short* lAw, int l, float* out) {
  const int4* lrow = (const int4*)(lAw + l * HD);
#pragma unroll
  for (int g = 0; g < 16; g++) {
    int4 v = lrow[g ^ (l & 7)];
    u32 a = (u32)v.x, b = (u32)v.y, cc = (u32)v.z, d = (u32)v.w;
    out[0 * 16 + g] = bf2f((u16)(a & 0xffffu));
    out[1 * 16 + g] = bf2f((u16)(a >> 16));
    out[2 * 16 + g] = bf2f((u16)(b & 0xffffu));
    out[3 * 16 + g] = bf2f((u16)(b >> 16));
    out[4 * 16 + g] = bf2f((u16)(cc & 0xffffu));
    out[5 * 16 + g] = bf2f((u16)(cc >> 16));
    out[6 * 16 + g] = bf2f((u16)(d & 0xffffu));
    out[7 * 16 + g] = bf2f((u16)(d >> 16));
  }
}

// ---------------- weight prep ----------------
__global__ __launch_bounds__(256) void k_prep(
    const void* __restrict__ mW1, const void* __restrict__ mW2,
    const void* __restrict__ uW1, const void* __restrict__ uW2,
    const void* __restrict__ oW1, const void* __restrict__ oW2,
    const int* __restrict__ flagp,
    u16* __restrict__ Wt1, u16* __restrict__ Wt2p,
    u16* __restrict__ Wtu1, u16* __restrict__ Wtu2p,
    u16* __restrict__ Wto1, u16* __restrict__ Wto2p) {
  const int mode = *flagp;
  const int tid = blockIdx.x * blockDim.x + threadIdx.x;
  const int stride = gridDim.x * blockDim.x;
  for (int i = tid; i < NL * HD * 384; i += stride) {
    int l = i / (HD * 384), r = i % (HD * 384), n = r / 384, k = r % 384;
    Wt1[i] = ldinb(mW1, ((size_t)l * 384 + k) * HD + n, mode);
  }
  for (int i = tid; i < NL * HD * HD; i += stride) {
    int l = i / (HD * HD), r = i % (HD * HD), n = r / HD, k = r % HD;
    int h = ((k & 7) << 4) | (k >> 3);
    Wt2p[i] = ldinb(mW2, ((size_t)l * HD + h) * HD + n, mode);
    Wtu1[i] = ldinb(uW1, ((size_t)l * HD + k) * HD + n, mode);
    Wtu2p[i] = ldinb(uW2, ((size_t)l * HD + h) * HD + n, mode);
  }
  for (int i = tid; i < HD * HD; i += stride) {
    int n = i / HD, k = i % HD;
    int h = ((k & 7) << 4) | (k >> 3);
    Wto1[i] = ldinb(oW1, (size_t)k * HD + n, mode);
    Wto2p[i] = ldinb(oW2, (size_t)h * HD + n, mode);
  }
}

// ---------------- feat init ----------------
__global__ __launch_bounds__(256) void k_featinit(const void* __restrict__ nemb,
                                                  const int* __restrict__ flagp,
                                                  u16* __restrict__ feat) {
  const int mode = *flagp;
  const int i = blockIdx.x * 256 + threadIdx.x;
  const int g = i & 15;
  u32 ou[4];
#pragma unroll
  for (int p = 0; p < 4; p++) {
    u16 a = ldinb(nemb, g * 8 + 2 * p, mode);
    u16 b = ldinb(nemb, g * 8 + 2 * p + 1, mode);
    ou[p] = (u32)a | ((u32)b << 16);
  }
  ((int4*)feat)[i] = make_int4((int)ou[0], (int)ou[1], (int)ou[2], (int)ou[3]);
}

// ---------------- edge feature encode ----------------
__global__ __launch_bounds__(256) void k_encode(const void* __restrict__ d,
                                                const void* __restrict__ We,
                                                const void* __restrict__ be,
                                                const int* __restrict__ flagp,
                                                u16* __restrict__ e) {
  const int mode = *flagp;
  __shared__ float sW[9 * HD];
  __shared__ float sb[HD];
  for (int i = threadIdx.x; i < 9 * HD; i += 256) sW[i] = ldinf(We, i, mode);
  for (int i = threadIdx.x; i < HD; i += 256) sb[i] = ldinf(be, i, mode);
  __syncthreads();
  const int eid = blockIdx.x * 256 + threadIdx.x;
  const float dv = ldinf(d, eid, mode);
  float de[9];
#pragma unroll
  for (int k = 0; k < 4; k++) {
    float x = dv * (1.0f / (float)(1 << k));
    de[k] = __sinf(x);
    de[4 + k] = __cosf(x);
  }
  de[8] = dv;
  u16* erow = e + (size_t)eid * HD;
#pragma unroll
  for (int hb = 0; hb < 16; hb++) {
    u32 ou[4];
#pragma unroll
    for (int p = 0; p < 4; p++) {
      float vv[2];
#pragma unroll
      for (int t = 0; t < 2; t++) {
        const int h = hb * 8 + 2 * p + t;
        float a = sb[h];
#pragma unroll
        for (int k = 0; k < 9; k++) a += de[k] * sW[k * HD + h];
        vv[t] = siluf(siluf(a));
      }
      ou[p] = pk2(vv[0], vv[1]);
    }
    ((int4*)erow)[hb] = make_int4((int)ou[0], (int)ou[1], (int)ou[2], (int)ou[3]);
  }
}

// ---------------- edge message layer (the heavy kernel) ----------------
// GEMM1 A-fragments come straight from global (feat[src], feat[dst], e rows).
// LDS used only for the h1 -> GEMM2 -> m round trip.
__global__ __launch_bounds__(64, 2) void k_edge(
    const u16* __restrict__ feat, u16* __restrict__ e,
    const int* __restrict__ src, const int* __restrict__ dstp,
    const u16* __restrict__ Wt1, const u16* __restrict__ Wt2p,
    const void* __restrict__ b1g, const void* __restrict__ b2g,
    const void* __restrict__ softW, const void* __restrict__ softb,
    const int* __restrict__ flagp, float* __restrict__ msum, int layer) {
  __shared__ __align__(16) short lM[64 * HD];
  __shared__ float swg[64];
  __shared__ int sdst[64];
  const int mode = *flagp;
  const int l = threadIdx.x;
  const int c = l & 15, kg = l >> 4;
  const int blk = blockIdx.x * 64;
  const int myedge = blk + l;
  sdst[l] = dstp[myedge];

  // fragment row offsets (shorts) for the 3 GEMM1 sources
  size_t offS[4], offD[4], offE[4];
#pragma unroll
  for (int mt = 0; mt < 4; mt++) {
    const int eidx = blk + mt * 16 + c;
    offS[mt] = (size_t)src[eidx] * HD;
    offD[mt] = (size_t)dstp[eidx] * HD;
    offE[mt] = (size_t)eidx * HD;
  }

  const u16* W1l = Wt1 + (size_t)layer * HD * 384;
  const u16* W2l = Wt2p + (size_t)layer * HD * HD;
  float bias1[8], bias2[8];
#pragma unroll
  for (int nt = 0; nt < 8; nt++) {
    bias1[nt] = ldinf(b1g, layer * HD + nt * 16 + c, mode);
    bias2[nt] = ldinf(b2g, layer * HD + nt * 16 + c, mode);
  }

  f32x4 acc[4][8];
  acc_zero(acc);
  // GEMM1: mi = [feat[src] | feat[dst] | e] @ W1, all A-frags direct from global
  gemm_g<384>(feat, offS, W1l, c, kg, acc);
  gemm_g<384>(feat, offD, W1l + 128, c, kg, acc);
  gemm_g<384>(e, offE, W1l + 256, c, kg, acc);
  wave_pack<true>(lM, c, kg, acc, bias1);   // h1 = silu(. + b1), k_new order
  __syncthreads();

  acc_zero(acc);
  wave_gemm<4, HD>(lM, W2l, c, kg, acc);    // h1 @ W2 (k-permuted weights)
  __syncthreads();
  wave_pack<true>(lM, c, kg, acc, bias2);   // m = silu(. + b2)
  __syncthreads();

  // ---- per-lane epilogue: gate + e-residual for own row ----
  float mf[128];
  read_row_h(lM, l, mf);

  float wp0 = 0.f, wp1 = 0.f, wp2 = 0.f, wp3 = 0.f;
#pragma unroll
  for (int h = 0; h < HD; h += 4) {
    wp0 += mf[h] * ldinf(softW, (size_t)layer * HD + h, mode);
    wp1 += mf[h + 1] * ldinf(softW, (size_t)layer * HD + h + 1, mode);
    wp2 += mf[h + 2] * ldinf(softW, (size_t)layer * HD + h + 2, mode);
    wp3 += mf[h + 3] * ldinf(softW, (size_t)layer * HD + h + 3, mode);
  }
  const float wdot = ldinf(softb, layer, mode) + ((wp0 + wp1) + (wp2 + wp3));
  swg[l] = sigf(wdot);

  u16* erow = e + (size_t)myedge * HD;
#pragma unroll
  for (int hb = 0; hb < 16; hb++) {
    int4 v = ((const int4*)erow)[hb];
    u32 uu[4] = {(u32)v.x, (u32)v.y, (u32)v.z, (u32)v.w};
    u32 ou[4];
#pragma unroll
    for (int p = 0; p < 4; p++) {
      float e0 = bf2f((u16)(uu[p] & 0xffffu)) + mf[hb * 8 + 2 * p];
      float e1 = bf2f((u16)(uu[p] >> 16)) + mf[hb * 8 + 2 * p + 1];
      ou[p] = pk2(e0, e1);
    }
    ((int4*)erow)[hb] = make_int4((int)ou[0], (int)ou[1], (int)ou[2], (int)ou[3]);
  }
  __syncthreads();

  // ---- cooperative, coalesced msum atomics: lane l covers h=l and h=l+64 ----
  const int j1 = l >> 4;
  const int goff = l & 15;
#pragma unroll 4
  for (int r = 0; r < 64; r++) {
    const int base = r * HD + ((goff ^ (r & 7)) << 3) + j1;
    const float v1 = bf2f((u16)lM[base]);       // h = l
    const float v2 = bf2f((u16)lM[base + 4]);   // h = l + 64
    const float wgr = swg[r];
    float* mrow = msum + (size_t)sdst[r] * HD;
    atomicAdd(&mrow[l], v1 * wgr);
    atomicAdd(&mrow[l + 64], v2 * wgr);
  }
}

// ---------------- node update layer ----------------
__global__ __launch_bounds__(64, 2) void k_node(
    u16* __restrict__ feat, const float* __restrict__ msum,
    const u16* __restrict__ Wtu1, const u16* __restrict__ Wtu2p,
    const void* __restrict__ b1g, const void* __restrict__ b2g,
    const int* __restrict__ flagp, int layer) {
  __shared__ __align__(16) short lA[64 * HD];
  const int mode = *flagp;
  const int l = threadIdx.x;
  const int c = l & 15, kg = l >> 4;
  short* lAw = lA;
  const int myrow = blockIdx.x * 64 + l;
  u16* frow = feat + (size_t)myrow * HD;
  const float* mrow = msum + (size_t)myrow * HD;
  const u16* W1l = Wtu1 + (size_t)layer * HD * HD;
  const u16* W2l = Wtu2p + (size_t)layer * HD * HD;
  float bias1[8], bias2[8];
#pragma unroll
  for (int nt = 0; nt < 8; nt++) {
    bias1[nt] = ldinf(b1g, layer * HD + nt * 16 + c, mode);
    bias2[nt] = ldinf(b2g, layer * HD + nt * 16 + c, mode);
  }
  {
    int4* lrow = (int4*)(lAw + l * HD);
#pragma unroll
    for (int g = 0; g < 16; g++) {
      int4 fv = ((const int4*)frow)[g];
      u32 uu[4] = {(u32)fv.x, (u32)fv.y, (u32)fv.z, (u32)fv.w};
      float4 ma = ((const float4*)mrow)[2 * g];
      float4 mb = ((const float4*)mrow)[2 * g + 1];
      float mm[8] = {ma.x, ma.y, ma.z, ma.w, mb.x, mb.y, mb.z, mb.w};
      u32 ou[4];
#pragma unroll
      for (int p = 0; p < 4; p++) {
        float a0 = bf2f((u16)(uu[p] & 0xffffu)) + mm[2 * p];
        float a1 = bf2f((u16)(uu[p] >> 16)) + mm[2 * p + 1];
        ou[p] = pk2(a0, a1);
      }
      lrow[g ^ (l & 7)] = make_int4((int)ou[0], (int)ou[1], (int)ou[2], (int)ou[3]);
    }
  }
  __syncthreads();
  f32x4 acc[4][8];
  acc_zero(acc);
  wave_gemm<4, HD>(lAw, W1l, c, kg, acc);
  __syncthreads();
  wave_pack<true>(lAw, c, kg, acc, bias1);
  __syncthreads();
  acc_zero(acc);
  wave_gemm<4, HD>(lAw, W2l, c, kg, acc);
  __syncthreads();
  wave_pack<false>(lAw, c, kg, acc, bias2);
  __syncthreads();

  float rf[128];
  read_row_h(lAw, l, rf);
#pragma unroll
  for (int hb = 0; hb < 16; hb++) {
    int4 fv = ((const int4*)frow)[hb];
    u32 uu[4] = {(u32)fv.x, (u32)fv.y, (u32)fv.z, (u32)fv.w};
    u32 ou[4];
#pragma unroll
    for (int p = 0; p < 4; p++) {
      float a0 = bf2f((u16)(uu[p] & 0xffffu)) + rf[hb * 8 + 2 * p];
      float a1 = bf2f((u16)(uu[p] >> 16)) + rf[hb * 8 + 2 * p + 1];
      ou[p] = pk2(a0, a1);
    }
    ((int4*)frow)[hb] = make_int4((int)ou[0], (int)ou[1], (int)ou[2], (int)ou[3]);
  }
}

// ---------------- output MLP + readout ----------------
__global__ __launch_bounds__(64, 2) void k_out(
    const u16* __restrict__ feat, const int* __restrict__ seg,
    const u16* __restrict__ Wto1, const u16* __restrict__ Wto2p,
    const void* __restrict__ ob1, const void* __restrict__ ob2,
    const int* __restrict__ flagp,
    float* __restrict__ sacc, u32* __restrict__ mxacc, float* __restrict__ cnt) {
  __shared__ __align__(16) short lA[64 * HD];
  __shared__ int sseg[64];
  const int mode = *flagp;
  const int l = threadIdx.x;
  const int c = l & 15, kg = l >> 4;
  short* lAw = lA;
  const int myrow = blockIdx.x * 64 + l;
  const u16* frow = feat + (size_t)myrow * HD;
  float bias1[8], bias2[8];
#pragma unroll
  for (int nt = 0; nt < 8; nt++) {
    bias1[nt] = ldinf(ob1, nt * 16 + c, mode);
    bias2[nt] = ldinf(ob2, nt * 16 + c, mode);
  }
  {
    int4* lrow = (int4*)(lAw + l * HD);
#pragma unroll
    for (int g = 0; g < 16; g++) lrow[g ^ (l & 7)] = ((const int4*)frow)[g];
  }
  sseg[l] = seg[myrow];
  __syncthreads();
  f32x4 acc[4][8];
  acc_zero(acc);
  wave_gemm<4, HD>(lAw, Wto1, c, kg, acc);
  __syncthreads();
  wave_pack<true>(lAw, c, kg, acc, bias1);
  __syncthreads();
  acc_zero(acc);
  wave_gemm<4, HD>(lAw, Wto2p, c, kg, acc);
  __syncthreads();
  wave_pack<false>(lAw, c, kg, acc, bias2);
  __syncthreads();

  const int j1 = l >> 4;
  const int goff = l & 15;
  const bool uniform = (sseg[0] == sseg[63]);
  if (uniform) {
    const int g = sseg[0];
    float s1 = 0.f, s2 = 0.f, x1 = -3.402823e38f, x2 = -3.402823e38f;
#pragma unroll 4
    for (int r = 0; r < 64; r++) {
      const int base = r * HD + ((goff ^ (r & 7)) << 3) + j1;
      const float v1 = bf2f((u16)lAw[base]);
      const float v2 = bf2f((u16)lAw[base + 4]);
      s1 += v1; s2 += v2;
      x1 = fmaxf(x1, v1); x2 = fmaxf(x2, v2);
    }
    atomicAdd(&sacc[(size_t)g * HD + l], s1);
    atomicAdd(&sacc[(size_t)g * HD + l + 64], s2);
    atomicMax(&mxacc[(size_t)g * HD + l], ordu(x1));
    atomicMax(&mxacc[(size_t)g * HD + l + 64], ordu(x2));
    if (l == 0) atomicAdd(&cnt[g], 64.0f);
  } else {
    atomicAdd(&cnt[sseg[l]], 1.0f);
#pragma unroll 4
    for (int r = 0; r < 64; r++) {
      const int base = r * HD + ((goff ^ (r & 7)) << 3) + j1;
      const float v1 = bf2f((u16)lAw[base]);
      const float v2 = bf2f((u16)lAw[base + 4]);
      const int g = sseg[r];
      atomicAdd(&sacc[(size_t)g * HD + l], v1);
      atomicAdd(&sacc[(size_t)g * HD + l + 64], v2);
      atomicMax(&mxacc[(size_t)g * HD + l], ordu(v1));
      atomicMax(&mxacc[(size_t)g * HD + l + 64], ordu(v2));
    }
  }
}

// ---------------- finalize ----------------
__global__ __launch_bounds__(256) void k_final(const float* __restrict__ sacc,
                                               const u32* __restrict__ mxacc,
                                               const float* __restrict__ cnt,
                                               const int* __restrict__ flagp,
                                               void* __restrict__ out) {
  const int mode = *flagp;
  const int i = blockIdx.x * 256 + threadIdx.x;
  const int b = i / 384, j = i % 384;
  float v;
  if (j < HD) v = sacc[b * HD + j];
  else if (j < 2 * HD) v = sacc[b * HD + (j - HD)] / fmaxf(cnt[b], 1.0f);
  else {
    u32 u = mxacc[b * HD + (j - 2 * HD)];
    u32 bits = (u >> 31) ? (u ^ 0x80000000u) : ~u;
    v = __uint_as_float(bits);
  }
  if (mode) ((float*)out)[i] = v;
  else ((u16*)out)[i] = f2bf(v);
}

extern "C" void kernel_launch(void* const* d_in, const int* in_sizes, int n_in,
                              void* d_out, int out_size, void* d_ws, size_t ws_size,
                              hipStream_t stream) {
  const void* d_d = d_in[0];
  const int* src = (const int*)d_in[1];
  const int* dst = (const int*)d_in[2];
  const int* seg = (const int*)d_in[3];
  const void* nemb = d_in[4];
  const void* We = d_in[5];
  const void* be = d_in[6];
  const void* mW1 = d_in[7];
  const void* mb1 = d_in[8];
  const void* mW2 = d_in[9];
  const void* mb2 = d_in[10];
  const void* sW = d_in[11];
  const void* sb = d_in[12];
  const void* uW1 = d_in[13];
  const void* ub1 = d_in[14];
  const void* uW2 = d_in[15];
  const void* ub2 = d_in[16];
  const void* oW1 = d_in[17];
  const void* ob1 = d_in[18];
  const void* oW2 = d_in[19];
  const void* ob2 = d_in[20];

  char* ws = (char*)d_ws;
  const size_t OFF_E = 0;
  const size_t OFF_MSUM = OFF_E + (size_t)NE * HD * 2;
  const size_t OFF_FEAT = OFF_MSUM + (size_t)NN * HD * 4;
  const size_t OFF_SACC = OFF_FEAT + (size_t)NN * HD * 2;
  const size_t OFF_MX = OFF_SACC + (size_t)NB * HD * 4;
  const size_t OFF_CNT = OFF_MX + (size_t)NB * HD * 4;
  const size_t OFF_WT1 = OFF_CNT + 1024;
  const size_t OFF_WT2P = OFF_WT1 + (size_t)NL * HD * 384 * 2;
  const size_t OFF_WTU1 = OFF_WT2P + (size_t)NL * HD * HD * 2;
  const size_t OFF_WTU2P = OFF_WTU1 + (size_t)NL * HD * HD * 2;
  const size_t OFF_WTO1 = OFF_WTU2P + (size_t)NL * HD * HD * 2;
  const size_t OFF_WTO2P = OFF_WTO1 + (size_t)HD * HD * 2;
  const size_t OFF_FLAG = OFF_WTO2P + (size_t)HD * HD * 2;

  u16* e = (u16*)(ws + OFF_E);
  float* msum = (float*)(ws + OFF_MSUM);
  u16* feat = (u16*)(ws + OFF_FEAT);
  float* sacc = (float*)(ws + OFF_SACC);
  u32* mx = (u32*)(ws + OFF_MX);
  float* cnt = (float*)(ws + OFF_CNT);
  u16* Wt1 = (u16*)(ws + OFF_WT1);
  u16* Wt2p = (u16*)(ws + OFF_WT2P);
  u16* Wtu1 = (u16*)(ws + OFF_WTU1);
  u16* Wtu2p = (u16*)(ws + OFF_WTU2P);
  u16* Wto1 = (u16*)(ws + OFF_WTO1);
  u16* Wto2p = (u16*)(ws + OFF_WTO2P);
  int* flag = (int*)(ws + OFF_FLAG);

  hipMemsetAsync(ws + OFF_SACC, 0, (size_t)NB * HD * 4 * 2 + 1024, stream);

  k_detect<<<1, 64, 0, stream>>>((const u16*)We, flag);
  k_prep<<<256, 256, 0, stream>>>(mW1, mW2, uW1, uW2, oW1, oW2, flag,
                                  Wt1, Wt2p, Wtu1, Wtu2p, Wto1, Wto2p);
  k_featinit<<<(NN * HD / 8) / 256, 256, 0, stream>>>(nemb, flag, feat);
  k_encode<<<NE / 256, 256, 0, stream>>>(d_d, We, be, flag, e);

  for (int l = 0; l < NL; l++) {
    hipMemsetAsync(msum, 0, (size_t)NN * HD * 4, stream);
    k_edge<<<NE / 64, 64, 0, stream>>>(feat, e, src, dst, Wt1, Wt2p,
                                       mb1, mb2, sW, sb, flag, msum, l);
    k_node<<<NN / 64, 64, 0, stream>>>(feat, msum, Wtu1, Wtu2p, ub1, ub2, flag, l);
  }
  k_out<<<NN / 64, 64, 0, stream>>>(feat, seg, Wto1, Wto2p, ob1, ob2, flag, sacc, mx, cnt);
  k_final<<<(NB * 384) / 256, 256, 0, stream>>>(sacc, mx, cnt, flag, d_out);
}

// Round 5
// 1132.643 us; speedup vs baseline: 1.0219x; 1.0219x over previous
//
#include <hip/hip_runtime.h>

#define NN 32768   // nodes
#define NB 256     // graphs
#define HD 128     // hidden
#define NL 4       // layers
#define NE 262144  // edges

typedef short bf16x8 __attribute__((ext_vector_type(8)));
typedef float f32x4 __attribute__((ext_vector_type(4)));
typedef unsigned short u16;
typedef unsigned int u32;

__device__ __forceinline__ float bf2f(u16 u) {
  return __uint_as_float(((u32)u) << 16);
}
__device__ __forceinline__ u16 f2bf(float f) {
  u32 x = __float_as_uint(f);
  u32 r = x + 0x7FFFu + ((x >> 16) & 1u);
  return (u16)(r >> 16);
}
__device__ __forceinline__ u32 pk2(float a, float b) {
  return (u32)f2bf(a) | ((u32)f2bf(b) << 16);
}
__device__ __forceinline__ float siluf(float x) {
  return x * __builtin_amdgcn_rcpf(1.0f + __expf(-x));
}
__device__ __forceinline__ float sigf(float x) {
  return __builtin_amdgcn_rcpf(1.0f + __expf(-x));
}
__device__ __forceinline__ u32 ordu(float f) {
  u32 b = __float_as_uint(f);
  return (b & 0x80000000u) ? ~b : (b | 0x80000000u);
}

// ---- adaptive input loads: mode 1 = f32 inputs, mode 0 = bf16 inputs ----
__device__ __forceinline__ float ldinf(const void* p, size_t i, int mode) {
  return mode ? ((const float*)p)[i] : bf2f(((const u16*)p)[i]);
}
__device__ __forceinline__ u16 ldinb(const void* p, size_t i, int mode) {
  return mode ? f2bf(((const float*)p)[i]) : ((const u16*)p)[i];
}

// ---- dtype detector (confirmed mode=1/f32; kept as cheap guard) ----
__global__ void k_detect(const u16* __restrict__ Weraw, int* __restrict__ flag) {
  if (threadIdx.x == 0 && blockIdx.x == 0) {
    int cnt = 0;
    for (int i = 0; i < 256; i++) {
      u16 u = Weraw[2 * i];
      u32 e = (u >> 7) & 0xFFu;
      if (e >= 112u && e <= 126u) cnt++;
    }
    *flag = (cnt >= 128) ? 0 : 1;
  }
}

// ---------------- per-wave GEMM pieces ----------------
// Wave tile: 64 rows x 128 cols, mfma_f32_16x16x32_bf16.
// A-frag: lane l holds A[row=(l&15)+16*mt][k=(l>>4)*8+j]  (16B contiguous)
// C/D: col = lane&15, row = (lane>>4)*4 + reg  (m89-verified)
// LDS tile: [64 rows][128 shorts], XOR-swizzled 16B granules:
//   granule_lds = granule_logical ^ (row & 7)
// Packed k_new order: granule g element j <-> h = j*16 + g
//   => lane l's h=l value: short offset r*HD + ((l&15)^(r&7))*8 + (l>>4); h=l+64 at +4.

__device__ __forceinline__ void acc_zero(f32x4 (&acc)[4][8]) {
#pragma unroll
  for (int mt = 0; mt < 4; mt++)
#pragma unroll
    for (int nt = 0; nt < 8; nt++) acc[mt][nt] = f32x4{0.f, 0.f, 0.f, 0.f};
}

// GEMM with A-fragments loaded DIRECTLY from global rows (no LDS staging).
template <int BSTRIDE>
__device__ __forceinline__ void gemm_g(const u16* __restrict__ A0,
                                       const size_t* rowoff,
                                       const u16* __restrict__ Bp,
                                       int c, int kg, f32x4 (&acc)[4][8]) {
#pragma unroll
  for (int ks = 0; ks < 4; ks++) {
    bf16x8 a[4];
#pragma unroll
    for (int mt = 0; mt < 4; mt++)
      a[mt] = *(const bf16x8*)&A0[rowoff[mt] + ks * 32 + kg * 8];
#pragma unroll
    for (int nt = 0; nt < 8; nt++) {
      bf16x8 b = *(const bf16x8*)&Bp[(nt * 16 + c) * BSTRIDE + ks * 32 + kg * 8];
#pragma unroll
      for (int mt = 0; mt < 4; mt++)
        acc[mt][nt] = __builtin_amdgcn_mfma_f32_16x16x32_bf16(a[mt], b, acc[mt][nt], 0, 0, 0);
    }
  }
}

// GEMM with A from swizzled LDS tile
template <int KSTEPS, int BSTRIDE>
__device__ __forceinline__ void wave_gemm(const short* lAw, const u16* Bp,
                                          int c, int kg, f32x4 (&acc)[4][8]) {
#pragma unroll
  for (int ks = 0; ks < KSTEPS; ks++) {
    bf16x8 a[4];
#pragma unroll
    for (int mt = 0; mt < 4; mt++) {
      const int r = mt * 16 + c;
      const int k = ks * 32 + kg * 8;
      a[mt] = *(const bf16x8*)&lAw[r * HD + (k ^ ((r & 7) << 3))];
    }
#pragma unroll
    for (int nt = 0; nt < 8; nt++) {
      bf16x8 b = *(const bf16x8*)&Bp[(nt * 16 + c) * BSTRIDE + ks * 32 + kg * 8];
#pragma unroll
      for (int mt = 0; mt < 4; mt++)
        acc[mt][nt] = __builtin_amdgcn_mfma_f32_16x16x32_bf16(a[mt], b, acc[mt][nt], 0, 0, 0);
    }
  }
}

template <bool SILU>
__device__ __forceinline__ void wave_pack(short* lAw, int c, int kg,
                                          f32x4 (&acc)[4][8], const float* bias) {
#pragma unroll
  for (int mt = 0; mt < 4; mt++) {
#pragma unroll
    for (int rr = 0; rr < 4; rr++) {
      const int row = mt * 16 + kg * 4 + rr;
      u32 ou[4];
#pragma unroll
      for (int p = 0; p < 4; p++) {
        float x0 = acc[mt][2 * p][rr] + bias[2 * p];
        float x1 = acc[mt][2 * p + 1][rr] + bias[2 * p + 1];
        if (SILU) { x0 = siluf(x0); x1 = siluf(x1); }
        ou[p] = pk2(x0, x1);
      }
      ((int4*)(lAw + row * HD))[c ^ (row & 7)] =
          make_int4((int)ou[0], (int)ou[1], (int)ou[2], (int)ou[3]);
    }
  }
}

// ---------------- weight prep ----------------
__global__ __launch_bounds__(256) void k_prep(
    const void* __restrict__ mW1, const void* __restrict__ mW2,
    const void* __restrict__ uW1, const void* __restrict__ uW2,
    const void* __restrict__ oW1, const void* __restrict__ oW2,
    const int* __restrict__ flagp,
    u16* __restrict__ Wt1, u16* __restrict__ Wt2p,
    u16* __restrict__ Wtu1, u16* __restrict__ Wtu2p,
    u16* __restrict__ Wto1, u16* __restrict__ Wto2p) {
  const int mode = *flagp;
  const int tid = blockIdx.x * blockDim.x + threadIdx.x;
  const int stride = gridDim.x * blockDim.x;
  for (int i = tid; i < NL * HD * 384; i += stride) {
    int l = i / (HD * 384), r = i % (HD * 384), n = r / 384, k = r % 384;
    Wt1[i] = ldinb(mW1, ((size_t)l * 384 + k) * HD + n, mode);
  }
  for (int i = tid; i < NL * HD * HD; i += stride) {
    int l = i / (HD * HD), r = i % (HD * HD), n = r / HD, k = r % HD;
    int h = ((k & 7) << 4) | (k >> 3);
    Wt2p[i] = ldinb(mW2, ((size_t)l * HD + h) * HD + n, mode);
    Wtu1[i] = ldinb(uW1, ((size_t)l * HD + k) * HD + n, mode);
    Wtu2p[i] = ldinb(uW2, ((size_t)l * HD + h) * HD + n, mode);
  }
  for (int i = tid; i < HD * HD; i += stride) {
    int n = i / HD, k = i % HD;
    int h = ((k & 7) << 4) | (k >> 3);
    Wto1[i] = ldinb(oW1, (size_t)k * HD + n, mode);
    Wto2p[i] = ldinb(oW2, (size_t)h * HD + n, mode);
  }
}

// ---------------- feat init ----------------
__global__ __launch_bounds__(256) void k_featinit(const void* __restrict__ nemb,
                                                  const int* __restrict__ flagp,
                                                  u16* __restrict__ feat) {
  const int mode = *flagp;
  const int i = blockIdx.x * 256 + threadIdx.x;
  const int g = i & 15;
  u32 ou[4];
#pragma unroll
  for (int p = 0; p < 4; p++) {
    u16 a = ldinb(nemb, g * 8 + 2 * p, mode);
    u16 b = ldinb(nemb, g * 8 + 2 * p + 1, mode);
    ou[p] = (u32)a | ((u32)b << 16);
  }
  ((int4*)feat)[i] = make_int4((int)ou[0], (int)ou[1], (int)ou[2], (int)ou[3]);
}

// ---------------- edge feature encode ----------------
__global__ __launch_bounds__(256) void k_encode(const void* __restrict__ d,
                                                const void* __restrict__ We,
                                                const void* __restrict__ be,
                                                const int* __restrict__ flagp,
                                                u16* __restrict__ e) {
  const int mode = *flagp;
  __shared__ float sW[9 * HD];
  __shared__ float sb[HD];
  for (int i = threadIdx.x; i < 9 * HD; i += 256) sW[i] = ldinf(We, i, mode);
  for (int i = threadIdx.x; i < HD; i += 256) sb[i] = ldinf(be, i, mode);
  __syncthreads();
  const int eid = blockIdx.x * 256 + threadIdx.x;
  const float dv = ldinf(d, eid, mode);
  float de[9];
#pragma unroll
  for (int k = 0; k < 4; k++) {
    float x = dv * (1.0f / (float)(1 << k));
    de[k] = __sinf(x);
    de[4 + k] = __cosf(x);
  }
  de[8] = dv;
  u16* erow = e + (size_t)eid * HD;
#pragma unroll
  for (int hb = 0; hb < 16; hb++) {
    u32 ou[4];
#pragma unroll
    for (int p = 0; p < 4; p++) {
      float vv[2];
#pragma unroll
      for (int t = 0; t < 2; t++) {
        const int h = hb * 8 + 2 * p + t;
        float a = sb[h];
#pragma unroll
        for (int k = 0; k < 9; k++) a += de[k] * sW[k * HD + h];
        vv[t] = siluf(siluf(a));
      }
      ou[p] = pk2(vv[0], vv[1]);
    }
    ((int4*)erow)[hb] = make_int4((int)ou[0], (int)ou[1], (int)ou[2], (int)ou[3]);
  }
}

// ---------------- edge message layer (the heavy kernel) ----------------
// GEMM1 A-frags direct from global; LDS only for h1 -> GEMM2 -> m round trip.
// Epilogue: gate computed from acc via cross-lane reduce (no 128-float array),
// e-residual + msum atomics fused in one cooperative per-row loop.
__global__ __launch_bounds__(64, 2) void k_edge(
    const u16* __restrict__ feat, u16* __restrict__ e,
    const int* __restrict__ src, const int* __restrict__ dstp,
    const u16* __restrict__ Wt1, const u16* __restrict__ Wt2p,
    const void* __restrict__ b1g, const void* __restrict__ b2g,
    const void* __restrict__ softW, const void* __restrict__ softb,
    const int* __restrict__ flagp, float* __restrict__ msum, int layer) {
  __shared__ __align__(16) short lM[64 * HD];
  __shared__ float swg[64];
  __shared__ int sdst[64];
  const int mode = *flagp;
  const int l = threadIdx.x;
  const int c = l & 15, kg = l >> 4;
  const int blk = blockIdx.x * 64;
  sdst[l] = dstp[blk + l];

  // fragment row offsets (shorts) for the 3 GEMM1 sources
  size_t offS[4], offD[4], offE[4];
#pragma unroll
  for (int mt = 0; mt < 4; mt++) {
    const int eidx = blk + mt * 16 + c;
    offS[mt] = (size_t)src[eidx] * HD;
    offD[mt] = (size_t)dstp[eidx] * HD;
    offE[mt] = (size_t)eidx * HD;
  }

  const u16* W1l = Wt1 + (size_t)layer * HD * 384;
  const u16* W2l = Wt2p + (size_t)layer * HD * HD;
  float bias1[8], bias2[8], swf[8];
#pragma unroll
  for (int nt = 0; nt < 8; nt++) {
    bias1[nt] = ldinf(b1g, layer * HD + nt * 16 + c, mode);
    bias2[nt] = ldinf(b2g, layer * HD + nt * 16 + c, mode);
    swf[nt] = ldinf(softW, (size_t)layer * HD + nt * 16 + c, mode);
  }
  const float sb = ldinf(softb, layer, mode);

  f32x4 acc[4][8];
  acc_zero(acc);
  // GEMM1: mi = [feat[src] | feat[dst] | e] @ W1
  gemm_g<384>(feat, offS, W1l, c, kg, acc);
  gemm_g<384>(feat, offD, W1l + 128, c, kg, acc);
  gemm_g<384>(e, offE, W1l + 256, c, kg, acc);
  wave_pack<true>(lM, c, kg, acc, bias1);   // h1 = silu(. + b1), k_new order
  __syncthreads();

  acc_zero(acc);
  wave_gemm<4, HD>(lM, W2l, c, kg, acc);    // h1 @ W2 (k-permuted weights)
  __syncthreads();

  // ---- fused pack + soft-gate (no per-lane 128-float array) ----
  float wred[4][4];
#pragma unroll
  for (int mt = 0; mt < 4; mt++) {
#pragma unroll
    for (int rr = 0; rr < 4; rr++) {
      const int row = mt * 16 + kg * 4 + rr;
      float mv[8];
      float wp = 0.f;
#pragma unroll
      for (int nt = 0; nt < 8; nt++) {
        mv[nt] = siluf(acc[mt][nt][rr] + bias2[nt]);
        wp += mv[nt] * swf[nt];
      }
      u32 ou[4];
#pragma unroll
      for (int p = 0; p < 4; p++) ou[p] = pk2(mv[2 * p], mv[2 * p + 1]);
      ((int4*)(lM + row * HD))[c ^ (row & 7)] =
          make_int4((int)ou[0], (int)ou[1], (int)ou[2], (int)ou[3]);
      wp += __shfl_xor(wp, 1);
      wp += __shfl_xor(wp, 2);
      wp += __shfl_xor(wp, 4);
      wp += __shfl_xor(wp, 8);
      wred[mt][rr] = wp;
    }
  }
#pragma unroll
  for (int mt = 0; mt < 4; mt++)
#pragma unroll
    for (int rr = 0; rr < 4; rr++)
      if (c == mt * 4 + rr) swg[mt * 16 + kg * 4 + rr] = sigf(wred[mt][rr] + sb);
  __syncthreads();

  // ---- cooperative per-row loop: e += m (coalesced u32 RMW) + msum atomics ----
  const int j1 = l >> 4;
  const int goff = l & 15;
  const bool hilane = (l >= 32);
  const int s0 = (2 * l) & 63, s1 = (2 * l + 1) & 63;
#pragma unroll 4
  for (int r = 0; r < 64; r++) {
    const int base = r * HD + ((goff ^ (r & 7)) << 3) + j1;
    const u32 m1 = (u16)lM[base];        // h = l
    const u32 m2 = (u16)lM[base + 4];    // h = l + 64
    const u32 pk = m1 | (m2 << 16);
    const float wgr = swg[r];
    // pair to (h=2l, 2l+1) for the coalesced e-row RMW
    const u32 a = (u32)__shfl((int)pk, s0);
    const u32 b = (u32)__shfl((int)pk, s1);
    const u32 lo = hilane ? (a >> 16) : (a & 0xffffu);
    const u32 hi = hilane ? (b >> 16) : (b & 0xffffu);
    u32* erow32 = (u32*)(e + (size_t)(blk + r) * HD);
    const u32 old = erow32[l];
    const float e0 = bf2f((u16)(old & 0xffffu)) + bf2f((u16)lo);
    const float e1 = bf2f((u16)(old >> 16)) + bf2f((u16)hi);
    erow32[l] = pk2(e0, e1);
    float* mrow = msum + (size_t)sdst[r] * HD;
    atomicAdd(&mrow[l], bf2f((u16)m1) * wgr);
    atomicAdd(&mrow[l + 64], bf2f((u16)m2) * wgr);
  }
}

// ---------------- node update layer ----------------
__global__ __launch_bounds__(64, 2) void k_node(
    u16* __restrict__ feat, const float* __restrict__ msum,
    const u16* __restrict__ Wtu1, const u16* __restrict__ Wtu2p,
    const void* __restrict__ b1g, const void* __restrict__ b2g,
    const int* __restrict__ flagp, int layer) {
  __shared__ __align__(16) short lA[64 * HD];
  const int mode = *flagp;
  const int l = threadIdx.x;
  const int c = l & 15, kg = l >> 4;
  short* lAw = lA;
  const int blkn = blockIdx.x * 64;
  const int myrow = blkn + l;
  u16* frow = feat + (size_t)myrow * HD;
  const float* mrow = msum + (size_t)myrow * HD;
  const u16* W1l = Wtu1 + (size_t)layer * HD * HD;
  const u16* W2l = Wtu2p + (size_t)layer * HD * HD;
  float bias1[8], bias2[8];
#pragma unroll
  for (int nt = 0; nt < 8; nt++) {
    bias1[nt] = ldinf(b1g, layer * HD + nt * 16 + c, mode);
    bias2[nt] = ldinf(b2g, layer * HD + nt * 16 + c, mode);
  }
  {
    int4* lrow = (int4*)(lAw + l * HD);
#pragma unroll
    for (int g = 0; g < 16; g++) {
      int4 fv = ((const int4*)frow)[g];
      u32 uu[4] = {(u32)fv.x, (u32)fv.y, (u32)fv.z, (u32)fv.w};
      float4 ma = ((const float4*)mrow)[2 * g];
      float4 mb = ((const float4*)mrow)[2 * g + 1];
      float mm[8] = {ma.x, ma.y, ma.z, ma.w, mb.x, mb.y, mb.z, mb.w};
      u32 ou[4];
#pragma unroll
      for (int p = 0; p < 4; p++) {
        float a0 = bf2f((u16)(uu[p] & 0xffffu)) + mm[2 * p];
        float a1 = bf2f((u16)(uu[p] >> 16)) + mm[2 * p + 1];
        ou[p] = pk2(a0, a1);
      }
      lrow[g ^ (l & 7)] = make_int4((int)ou[0], (int)ou[1], (int)ou[2], (int)ou[3]);
    }
  }
  __syncthreads();
  f32x4 acc[4][8];
  acc_zero(acc);
  wave_gemm<4, HD>(lAw, W1l, c, kg, acc);
  __syncthreads();
  wave_pack<true>(lAw, c, kg, acc, bias1);
  __syncthreads();
  acc_zero(acc);
  wave_gemm<4, HD>(lAw, W2l, c, kg, acc);
  __syncthreads();
  wave_pack<false>(lAw, c, kg, acc, bias2);
  __syncthreads();

  // cooperative feat residual: coalesced u32 RMW per row
  const int j1 = l >> 4;
  const int goff = l & 15;
  const bool hilane = (l >= 32);
  const int s0 = (2 * l) & 63, s1 = (2 * l + 1) & 63;
#pragma unroll 4
  for (int r = 0; r < 64; r++) {
    const int base = r * HD + ((goff ^ (r & 7)) << 3) + j1;
    const u32 m1 = (u16)lAw[base];
    const u32 m2 = (u16)lAw[base + 4];
    const u32 pk = m1 | (m2 << 16);
    const u32 a = (u32)__shfl((int)pk, s0);
    const u32 b = (u32)__shfl((int)pk, s1);
    const u32 lo = hilane ? (a >> 16) : (a & 0xffffu);
    const u32 hi = hilane ? (b >> 16) : (b & 0xffffu);
    u32* frow32 = (u32*)(feat + (size_t)(blkn + r) * HD);
    const u32 old = frow32[l];
    const float a0 = bf2f((u16)(old & 0xffffu)) + bf2f((u16)lo);
    const float a1 = bf2f((u16)(old >> 16)) + bf2f((u16)hi);
    frow32[l] = pk2(a0, a1);
  }
}

// ---------------- output MLP + readout ----------------
__global__ __launch_bounds__(64, 2) void k_out(
    const u16* __restrict__ feat, const int* __restrict__ seg,
    const u16* __restrict__ Wto1, const u16* __restrict__ Wto2p,
    const void* __restrict__ ob1, const void* __restrict__ ob2,
    const int* __restrict__ flagp,
    float* __restrict__ sacc, u32* __restrict__ mxacc, float* __restrict__ cnt) {
  __shared__ __align__(16) short lA[64 * HD];
  __shared__ int sseg[64];
  const int mode = *flagp;
  const int l = threadIdx.x;
  const int c = l & 15, kg = l >> 4;
  short* lAw = lA;
  const int myrow = blockIdx.x * 64 + l;
  const u16* frow = feat + (size_t)myrow * HD;
  float bias1[8], bias2[8];
#pragma unroll
  for (int nt = 0; nt < 8; nt++) {
    bias1[nt] = ldinf(ob1, nt * 16 + c, mode);
    bias2[nt] = ldinf(ob2, nt * 16 + c, mode);
  }
  {
    int4* lrow = (int4*)(lAw + l * HD);
#pragma unroll
    for (int g = 0; g < 16; g++) lrow[g ^ (l & 7)] = ((const int4*)frow)[g];
  }
  sseg[l] = seg[myrow];
  __syncthreads();
  f32x4 acc[4][8];
  acc_zero(acc);
  wave_gemm<4, HD>(lAw, Wto1, c, kg, acc);
  __syncthreads();
  wave_pack<true>(lAw, c, kg, acc, bias1);
  __syncthreads();
  acc_zero(acc);
  wave_gemm<4, HD>(lAw, Wto2p, c, kg, acc);
  __syncthreads();
  wave_pack<false>(lAw, c, kg, acc, bias2);
  __syncthreads();

  const int j1 = l >> 4;
  const int goff = l & 15;
  const bool uniform = (sseg[0] == sseg[63]);
  if (uniform) {
    const int g = sseg[0];
    float s1 = 0.f, s2 = 0.f, x1 = -3.402823e38f, x2 = -3.402823e38f;
#pragma unroll 4
    for (int r = 0; r < 64; r++) {
      const int base = r * HD + ((goff ^ (r & 7)) << 3) + j1;
      const float v1 = bf2f((u16)lAw[base]);
      const float v2 = bf2f((u16)lAw[base + 4]);
      s1 += v1; s2 += v2;
      x1 = fmaxf(x1, v1); x2 = fmaxf(x2, v2);
    }
    atomicAdd(&sacc[(size_t)g * HD + l], s1);
    atomicAdd(&sacc[(size_t)g * HD + l + 64], s2);
    atomicMax(&mxacc[(size_t)g * HD + l], ordu(x1));
    atomicMax(&mxacc[(size_t)g * HD + l + 64], ordu(x2));
    if (l == 0) atomicAdd(&cnt[g], 64.0f);
  } else {
    atomicAdd(&cnt[sseg[l]], 1.0f);
#pragma unroll 4
    for (int r = 0; r < 64; r++) {
      const int base = r * HD + ((goff ^ (r & 7)) << 3) + j1;
      const float v1 = bf2f((u16)lAw[base]);
      const float v2 = bf2f((u16)lAw[base + 4]);
      const int g = sseg[r];
      atomicAdd(&sacc[(size_t)g * HD + l], v1);
      atomicAdd(&sacc[(size_t)g * HD + l + 64], v2);
      atomicMax(&mxacc[(size_t)g * HD + l], ordu(v1));
      atomicMax(&mxacc[(size_t)g * HD + l + 64], ordu(v2));
    }
  }
}

// ---------------- finalize ----------------
__global__ __launch_bounds__(256) void k_final(const float* __restrict__ sacc,
                                               const u32* __restrict__ mxacc,
                                               const float* __restrict__ cnt,
                                               const int* __restrict__ flagp,
                                               void* __restrict__ out) {
  const int mode = *flagp;
  const int i = blockIdx.x * 256 + threadIdx.x;
  const int b = i / 384, j = i % 384;
  float v;
  if (j < HD) v = sacc[b * HD + j];
  else if (j < 2 * HD) v = sacc[b * HD + (j - HD)] / fmaxf(cnt[b], 1.0f);
  else {
    u32 u = mxacc[b * HD + (j - 2 * HD)];
    u32 bits = (u >> 31) ? (u ^ 0x80000000u) : ~u;
    v = __uint_as_float(bits);
  }
  if (mode) ((float*)out)[i] = v;
  else ((u16*)out)[i] = f2bf(v);
}

extern "C" void kernel_launch(void* const* d_in, const int* in_sizes, int n_in,
                              void* d_out, int out_size, void* d_ws, size_t ws_size,
                              hipStream_t stream) {
  const void* d_d = d_in[0];
  const int* src = (const int*)d_in[1];
  const int* dst = (const int*)d_in[2];
  const int* seg = (const int*)d_in[3];
  const void* nemb = d_in[4];
  const void* We = d_in[5];
  const void* be = d_in[6];
  const void* mW1 = d_in[7];
  const void* mb1 = d_in[8];
  const void* mW2 = d_in[9];
  const void* mb2 = d_in[10];
  const void* sW = d_in[11];
  const void* sb = d_in[12];
  const void* uW1 = d_in[13];
  const void* ub1 = d_in[14];
  const void* uW2 = d_in[15];
  const void* ub2 = d_in[16];
  const void* oW1 = d_in[17];
  const void* ob1 = d_in[18];
  const void* oW2 = d_in[19];
  const void* ob2 = d_in[20];

  char* ws = (char*)d_ws;
  const size_t OFF_E = 0;
  const size_t OFF_MSUM = OFF_E + (size_t)NE * HD * 2;
  const size_t OFF_FEAT = OFF_MSUM + (size_t)NN * HD * 4;
  const size_t OFF_SACC = OFF_FEAT + (size_t)NN * HD * 2;
  const size_t OFF_MX = OFF_SACC + (size_t)NB * HD * 4;
  const size_t OFF_CNT = OFF_MX + (size_t)NB * HD * 4;
  const size_t OFF_WT1 = OFF_CNT + 1024;
  const size_t OFF_WT2P = OFF_WT1 + (size_t)NL * HD * 384 * 2;
  const size_t OFF_WTU1 = OFF_WT2P + (size_t)NL * HD * HD * 2;
  const size_t OFF_WTU2P = OFF_WTU1 + (size_t)NL * HD * HD * 2;
  const size_t OFF_WTO1 = OFF_WTU2P + (size_t)NL * HD * HD * 2;
  const size_t OFF_WTO2P = OFF_WTO1 + (size_t)HD * HD * 2;
  const size_t OFF_FLAG = OFF_WTO2P + (size_t)HD * HD * 2;

  u16* e = (u16*)(ws + OFF_E);
  float* msum = (float*)(ws + OFF_MSUM);
  u16* feat = (u16*)(ws + OFF_FEAT);
  float* sacc = (float*)(ws + OFF_SACC);
  u32* mx = (u32*)(ws + OFF_MX);
  float* cnt = (float*)(ws + OFF_CNT);
  u16* Wt1 = (u16*)(ws + OFF_WT1);
  u16* Wt2p = (u16*)(ws + OFF_WT2P);
  u16* Wtu1 = (u16*)(ws + OFF_WTU1);
  u16* Wtu2p = (u16*)(ws + OFF_WTU2P);
  u16* Wto1 = (u16*)(ws + OFF_WTO1);
  u16* Wto2p = (u16*)(ws + OFF_WTO2P);
  int* flag = (int*)(ws + OFF_FLAG);

  hipMemsetAsync(ws + OFF_SACC, 0, (size_t)NB * HD * 4 * 2 + 1024, stream);

  k_detect<<<1, 64, 0, stream>>>((const u16*)We, flag);
  k_prep<<<256, 256, 0, stream>>>(mW1, mW2, uW1, uW2, oW1, oW2, flag,
                                  Wt1, Wt2p, Wtu1, Wtu2p, Wto1, Wto2p);
  k_featinit<<<(NN * HD / 8) / 256, 256, 0, stream>>>(nemb, flag, feat);
  k_encode<<<NE / 256, 256, 0, stream>>>(d_d, We, be, flag, e);

  for (int l = 0; l < NL; l++) {
    hipMemsetAsync(msum, 0, (size_t)NN * HD * 4, stream);
    k_edge<<<NE / 64, 64, 0, stream>>>(feat, e, src, dst, Wt1, Wt2p,
                                       mb1, mb2, sW, sb, flag, msum, l);
    k_node<<<NN / 64, 64, 0, stream>>>(feat, msum, Wtu1, Wtu2p, ub1, ub2, flag, l);
  }
  k_out<<<NN / 64, 64, 0, stream>>>(feat, seg, Wto1, Wto2p, ob1, ob2, flag, sacc, mx, cnt);
  k_final<<<(NB * 384) / 256, 256, 0, stream>>>(sacc, mx, cnt, flag, d_out);
}